// Round 6
// baseline (296.340 us; speedup 1.0000x reference)
//
#include <hip/hip_runtime.h>
#include <hip/hip_bf16.h>

// Problem constants (MoEAdaptorLayer_111669150283)
#define BATCH   512
#define LSEQ    50
#define DIN     768
#define DOUT    300
#define NEXP    8
#define NTOK    (BATCH * LSEQ)      // 25600

typedef __bf16 bf16_t;
typedef __attribute__((ext_vector_type(8))) __bf16 bf16x8;
typedef __attribute__((ext_vector_type(4))) float f32x4;

// async global->LDS, 16 B per lane, dst = wave-uniform base + lane*16
#define GLDS16(g, l) __builtin_amdgcn_global_load_lds( \
    (__attribute__((address_space(1))) void*)(g), \
    (__attribute__((address_space(3))) void*)(l), 16, 0, 0)

static __device__ __forceinline__ unsigned short f2bf(float f) {
    unsigned u = __float_as_uint(f);
    u = (u + 0x7fff + ((u >> 16) & 1)) >> 16;   // round-to-nearest-even
    return (unsigned short)u;
}

// ---------------------------------------------------------------------------
// Kernel 1 (merged prep): block-range split. VERBATIM R0 (verified, ~33 us).
//   blocks [0, 6400):    xb = bf16(x), gates = softmax(x @ w_gate)
//   blocks [6400, 7600): bw[l,e,o] = <bias[e,l,:], W[e,o,:]>, wb = bf16(W)
// ---------------------------------------------------------------------------
#define PREP_GATE_BLOCKS (NTOK / 4)              // 6400
#define PREP_BW_BLOCKS   ((2 * NEXP * DOUT) / 4) // 1200

__global__ __launch_bounds__(256) void prep_kernel(
    const float* __restrict__ x, const float* __restrict__ wg,
    const float* __restrict__ bias, const float* __restrict__ W,
    unsigned short* __restrict__ xb, float* __restrict__ gates,
    float* __restrict__ bw, unsigned short* __restrict__ wb)
{
    const int tid  = threadIdx.x;
    const int lane = tid & 63;

    if (blockIdx.x < PREP_GATE_BLOCKS) {
        __shared__ float wgT[NEXP][DIN + 4];   // transposed gate weights
        #pragma unroll
        for (int r = 0; r < 6; ++r) {
            int j = tid + 256 * r;             // float4 index 0..1535
            float4 v = ((const float4*)wg)[j];
            int i  = j >> 1;
            int e0 = (j & 1) * 4;
            wgT[e0 + 0][i] = v.x;
            wgT[e0 + 1][i] = v.y;
            wgT[e0 + 2][i] = v.z;
            wgT[e0 + 3][i] = v.w;
        }
        __syncthreads();

        int t = blockIdx.x * 4 + (tid >> 6);
        const float4* xr = (const float4*)(x + (size_t)t * DIN);
        ushort4* xo = (ushort4*)(xb + (size_t)t * DIN);

        float acc[NEXP];
        #pragma unroll
        for (int e = 0; e < NEXP; e++) acc[e] = 0.0f;

        #pragma unroll
        for (int k = 0; k < 3; ++k) {
            int i4 = lane + 64 * k;
            float4 v = xr[i4];
            ushort4 u;
            u.x = f2bf(v.x); u.y = f2bf(v.y); u.z = f2bf(v.z); u.w = f2bf(v.w);
            xo[i4] = u;
            #pragma unroll
            for (int e = 0; e < NEXP; ++e) {
                float4 wv = *(const float4*)&wgT[e][4 * i4];
                acc[e] += v.x * wv.x + v.y * wv.y + v.z * wv.z + v.w * wv.w;
            }
        }
        #pragma unroll
        for (int e = 0; e < NEXP; e++) {
            #pragma unroll
            for (int m = 32; m > 0; m >>= 1) acc[e] += __shfl_xor(acc[e], m, 64);
        }
        float mx = acc[0];
        #pragma unroll
        for (int e = 1; e < NEXP; e++) mx = fmaxf(mx, acc[e]);
        float ex[NEXP]; float s = 0.0f;
        #pragma unroll
        for (int e = 0; e < NEXP; e++) { ex[e] = __expf(acc[e] - mx); s += ex[e]; }
        float inv = 1.0f / s;
        if (lane == 0) {
            #pragma unroll
            for (int e = 0; e < NEXP; e++) gates[(size_t)t * NEXP + e] = ex[e] * inv;
        }
    } else {
        int wid  = (blockIdx.x - PREP_GATE_BLOCKS) * 4 + (tid >> 6);  // 0..4799
        int half = wid & 1;
        int eo   = wid >> 1;
        int e = eo / DOUT, o = eo % DOUT;

        const float4* wr = (const float4*)(W + ((size_t)e * DOUT + o) * DIN);
        float4 w4[3];
        #pragma unroll
        for (int k = 0; k < 3; ++k) w4[k] = wr[lane + 64 * k];

        if (half == 0) {
            ushort4* wo = (ushort4*)(wb + ((size_t)e * DOUT + o) * DIN);
            #pragma unroll
            for (int k = 0; k < 3; ++k) {
                ushort4 u;
                u.x = f2bf(w4[k].x); u.y = f2bf(w4[k].y);
                u.z = f2bf(w4[k].z); u.w = f2bf(w4[k].w);
                wo[lane + 64 * k] = u;
            }
        }

        int l0 = 25 * half;
        for (int l = l0; l < l0 + 25; ++l) {
            const float4* br = (const float4*)(bias + ((size_t)e * LSEQ + l) * DIN);
            float acc = 0.0f;
            #pragma unroll
            for (int k = 0; k < 3; ++k) {
                float4 b = br[lane + 64 * k];
                acc += b.x * w4[k].x + b.y * w4[k].y + b.z * w4[k].z + b.w * w4[k].w;
            }
            #pragma unroll
            for (int m = 32; m > 0; m >>= 1) acc += __shfl_xor(acc, m, 64);
            if (lane == 0) bw[((size_t)l * NEXP + e) * DOUT + o] = acc;
        }
    }
}

// ---------------------------------------------------------------------------
// Kernel 2 (ROUND 11): phased-schedule MFMA GEMM, 512 threads / 8 waves.
// R5 books: DS 1056 + MFMA 776 cyc/iter vs wall 2024 -> pipes NOT overlapping.
// Mechanism fix (catalog T3+T4+T5; m232's 4-wave null explained by 1 wave/SIMD
// per block -> barriers can't stagger): 8-wave blocks put 2 same-block waves
// per SIMD; phase barriers pace them into read||MFMA complement.
//   BM=512 x BN=128 (same 8-expert x 16-out o-major panel -> epilogue VERBATIM
//   R3), BK=32 (same 64B k-chunk swizzle -> staging/read offsets VERBATIM),
//   wave-tile 64x128 = rf4 x cf8, acc[4][8].
//   3-buffer LDS (3 x 40960 = 120 KB, 1 block/CU), depth-2 prefetch: tile j+2
//   staged during iter j, consumed at iter j+2 -> counted vmcnt(8), never 0.
//   Stage index wraps mod 24 (restages tile 0/1 into retired buffers) so the
//   tail needs no peeling and vmcnt stays uniform.
// Phase = {stage-issue -> ds_read -> lgkmcnt(0)+sched_barrier (rule 18) ->
//   setprio(1) -> 16-MFMA cluster -> setprio(0) -> s_barrier}.
// Hazards verified by issue-order counting:
//   - vmcnt(8): at iter-j wait, younger ops = 5 (tile j+1) + 3 (just issued)
//     = 8; tile j's 5 are older -> waited on. Prologue (10 issued) same.
//   - buf[(j+2)%3] writers vs readers: last reader = tile j-1 (same buf),
//     reads complete before its phase-end barrier; writes issue after.
// ---------------------------------------------------------------------------
#define BM8   512
#define NRT8  (NTOK / BM8)        // 50 row tiles
#define NOT8  19                  // o tiles (16 wide, clamp at 300)
#define RPG8  7                   // row-tiles per XCD group (8*7 = 56 >= 50)
#define NSLOT8 (8 * RPG8 * NOT8)  // 1064
#define KTN   (DIN / 32)          // 24 K-tiles
#define TBUF  40960               // per-tile buffer: A 32K | B 8K

__global__ __launch_bounds__(512, 2) void moe_mfma8_kernel(
    const bf16_t* __restrict__ xb, const bf16_t* __restrict__ wb,
    const float* __restrict__ gates, const float* __restrict__ bw,
    float* __restrict__ out)
{
    const int bid  = blockIdx.x;
    const int g    = bid & 7;
    const int slot = bid >> 3;
    const int r_in = slot / NOT8;
    const int o_t  = slot - NOT8 * r_in;
    const int r_t  = g * RPG8 + r_in;
    if (r_t >= NRT8) return;           // uniform early-exit, before any barrier
    const int o0 = o_t * 16;
    const int t0 = r_t * BM8;

    __shared__ __align__(16) char lds[3 * TBUF];   // 122880 B

    const int tid  = threadIdx.x;
    const int w    = tid >> 6;          // wave 0..7
    const int lane = tid & 63;

    // ---- staging addresses (swizzle verified rounds 2-5) ----
    const int srow4 = lane >> 2;                          // 0..15
    const int c16   = 16 * ((lane & 3) ^ ((lane >> 4) & 3));

    // A: round r covers rows r*128 + w*16 + srow4 (512 rows total)
    const char* xga[4];
    #pragma unroll
    for (int r = 0; r < 4; ++r)
        xga[r] = (const char*)xb + (size_t)(t0 + r * 128 + w * 16 + srow4) * (DIN * 2) + c16;

    // B: one round, n = w*16 + srow4 (0..127): e = n>>4, o = o0 + (n&15)
    const char* wga;
    {
        int n = w * 16 + srow4;
        int e = n >> 4;
        int o = o0 + (n & 15); if (o >= DOUT) o = DOUT - 1;  // clamp; guarded at store
        wga = (const char*)wb + (size_t)(e * DOUT + o) * (DIN * 2) + c16;
    }

    // ---- fragment read offsets (swizzled), relative to buffer base ----
    const int m = lane & 15, q = lane >> 4;
    const int sw = 16 * (q ^ ((m >> 2) & 3));
    int aoff[4], boff[8];
    #pragma unroll
    for (int rf = 0; rf < 4; ++rf) aoff[rf] = (w * 64 + rf * 16 + m) * 64 + sw;
    #pragma unroll
    for (int cf = 0; cf < 8; ++cf) boff[cf] = 32768 + (cf * 16 + m) * 64 + sw;

    f32x4 acc[4][8] = {};

    // ---- prologue: tile 0 -> buf0, tile 1 -> buf1 (no waits) ----
    #pragma unroll
    for (int r = 0; r < 4; ++r) GLDS16(xga[r], lds + r * 8192 + w * 1024);
    GLDS16(wga, lds + 32768 + w * 1024);
    #pragma unroll
    for (int r = 0; r < 4; ++r) GLDS16(xga[r] + 64, lds + TBUF + r * 8192 + w * 1024);
    GLDS16(wga + 64, lds + TBUF + 32768 + w * 1024);

    int cbuf = 0;
    for (int j = 0; j < KTN; ++j) {
        int s = j + 2; if (s >= KTN) s -= KTN;   // wrap: restage 0/1 at tail
        const int koff = s * 64;
        int sbuf = cbuf + 2; if (sbuf >= 3) sbuf -= 3;
        char* sb = lds + sbuf * TBUF;
        const char* cb = lds + cbuf * TBUF;

        // ===== phase 1: stage A rounds 0-2 | vmcnt(8) | read b[8],a0,a1 | MFMA rf0,1
        GLDS16(xga[0] + koff, sb + 0 * 8192 + w * 1024);
        GLDS16(xga[1] + koff, sb + 1 * 8192 + w * 1024);
        GLDS16(xga[2] + koff, sb + 2 * 8192 + w * 1024);
        asm volatile("s_waitcnt vmcnt(8)" ::: "memory");   // tile j's 5 done
        __builtin_amdgcn_s_barrier();                      // block-visible
        __builtin_amdgcn_sched_barrier(0);

        bf16x8 b0 = *(const bf16x8*)(cb + boff[0]);
        bf16x8 b1 = *(const bf16x8*)(cb + boff[1]);
        bf16x8 b2 = *(const bf16x8*)(cb + boff[2]);
        bf16x8 b3 = *(const bf16x8*)(cb + boff[3]);
        bf16x8 b4 = *(const bf16x8*)(cb + boff[4]);
        bf16x8 b5 = *(const bf16x8*)(cb + boff[5]);
        bf16x8 b6 = *(const bf16x8*)(cb + boff[6]);
        bf16x8 b7 = *(const bf16x8*)(cb + boff[7]);
        bf16x8 a0 = *(const bf16x8*)(cb + aoff[0]);
        bf16x8 a1 = *(const bf16x8*)(cb + aoff[1]);
        asm volatile("s_waitcnt lgkmcnt(0)" ::: "memory");
        __builtin_amdgcn_sched_barrier(0);
        __builtin_amdgcn_s_setprio(1);
        acc[0][0] = __builtin_amdgcn_mfma_f32_16x16x32_bf16(a0, b0, acc[0][0], 0, 0, 0);
        acc[0][1] = __builtin_amdgcn_mfma_f32_16x16x32_bf16(a0, b1, acc[0][1], 0, 0, 0);
        acc[0][2] = __builtin_amdgcn_mfma_f32_16x16x32_bf16(a0, b2, acc[0][2], 0, 0, 0);
        acc[0][3] = __builtin_amdgcn_mfma_f32_16x16x32_bf16(a0, b3, acc[0][3], 0, 0, 0);
        acc[0][4] = __builtin_amdgcn_mfma_f32_16x16x32_bf16(a0, b4, acc[0][4], 0, 0, 0);
        acc[0][5] = __builtin_amdgcn_mfma_f32_16x16x32_bf16(a0, b5, acc[0][5], 0, 0, 0);
        acc[0][6] = __builtin_amdgcn_mfma_f32_16x16x32_bf16(a0, b6, acc[0][6], 0, 0, 0);
        acc[0][7] = __builtin_amdgcn_mfma_f32_16x16x32_bf16(a0, b7, acc[0][7], 0, 0, 0);
        acc[1][0] = __builtin_amdgcn_mfma_f32_16x16x32_bf16(a1, b0, acc[1][0], 0, 0, 0);
        acc[1][1] = __builtin_amdgcn_mfma_f32_16x16x32_bf16(a1, b1, acc[1][1], 0, 0, 0);
        acc[1][2] = __builtin_amdgcn_mfma_f32_16x16x32_bf16(a1, b2, acc[1][2], 0, 0, 0);
        acc[1][3] = __builtin_amdgcn_mfma_f32_16x16x32_bf16(a1, b3, acc[1][3], 0, 0, 0);
        acc[1][4] = __builtin_amdgcn_mfma_f32_16x16x32_bf16(a1, b4, acc[1][4], 0, 0, 0);
        acc[1][5] = __builtin_amdgcn_mfma_f32_16x16x32_bf16(a1, b5, acc[1][5], 0, 0, 0);
        acc[1][6] = __builtin_amdgcn_mfma_f32_16x16x32_bf16(a1, b6, acc[1][6], 0, 0, 0);
        acc[1][7] = __builtin_amdgcn_mfma_f32_16x16x32_bf16(a1, b7, acc[1][7], 0, 0, 0);
        __builtin_amdgcn_s_setprio(0);
        __builtin_amdgcn_s_barrier();

        // ===== phase 2: stage A round 3 + B | read a2,a3 | MFMA rf2,3 (b reused)
        GLDS16(xga[3] + koff, sb + 3 * 8192 + w * 1024);
        GLDS16(wga + koff, sb + 32768 + w * 1024);
        bf16x8 a2 = *(const bf16x8*)(cb + aoff[2]);
        bf16x8 a3 = *(const bf16x8*)(cb + aoff[3]);
        asm volatile("s_waitcnt lgkmcnt(0)" ::: "memory");
        __builtin_amdgcn_sched_barrier(0);
        __builtin_amdgcn_s_setprio(1);
        acc[2][0] = __builtin_amdgcn_mfma_f32_16x16x32_bf16(a2, b0, acc[2][0], 0, 0, 0);
        acc[2][1] = __builtin_amdgcn_mfma_f32_16x16x32_bf16(a2, b1, acc[2][1], 0, 0, 0);
        acc[2][2] = __builtin_amdgcn_mfma_f32_16x16x32_bf16(a2, b2, acc[2][2], 0, 0, 0);
        acc[2][3] = __builtin_amdgcn_mfma_f32_16x16x32_bf16(a2, b3, acc[2][3], 0, 0, 0);
        acc[2][4] = __builtin_amdgcn_mfma_f32_16x16x32_bf16(a2, b4, acc[2][4], 0, 0, 0);
        acc[2][5] = __builtin_amdgcn_mfma_f32_16x16x32_bf16(a2, b5, acc[2][5], 0, 0, 0);
        acc[2][6] = __builtin_amdgcn_mfma_f32_16x16x32_bf16(a2, b6, acc[2][6], 0, 0, 0);
        acc[2][7] = __builtin_amdgcn_mfma_f32_16x16x32_bf16(a2, b7, acc[2][7], 0, 0, 0);
        acc[3][0] = __builtin_amdgcn_mfma_f32_16x16x32_bf16(a3, b0, acc[3][0], 0, 0, 0);
        acc[3][1] = __builtin_amdgcn_mfma_f32_16x16x32_bf16(a3, b1, acc[3][1], 0, 0, 0);
        acc[3][2] = __builtin_amdgcn_mfma_f32_16x16x32_bf16(a3, b2, acc[3][2], 0, 0, 0);
        acc[3][3] = __builtin_amdgcn_mfma_f32_16x16x32_bf16(a3, b3, acc[3][3], 0, 0, 0);
        acc[3][4] = __builtin_amdgcn_mfma_f32_16x16x32_bf16(a3, b4, acc[3][4], 0, 0, 0);
        acc[3][5] = __builtin_amdgcn_mfma_f32_16x16x32_bf16(a3, b5, acc[3][5], 0, 0, 0);
        acc[3][6] = __builtin_amdgcn_mfma_f32_16x16x32_bf16(a3, b6, acc[3][6], 0, 0, 0);
        acc[3][7] = __builtin_amdgcn_mfma_f32_16x16x32_bf16(a3, b7, acc[3][7], 0, 0, 0);
        __builtin_amdgcn_s_setprio(0);
        __builtin_amdgcn_s_barrier();   // all reads of cb done -> next iter may overwrite

        cbuf += 1; if (cbuf >= 3) cbuf -= 3;
    }

    // ---- epilogue: out[t,o] = sum_e g[t,e] * (acc - bw[l,e,o]) (VERBATIM R3,
    //      row base 64*w) ----
    const int o = o0 + m;
    if (o < DOUT) {
        #pragma unroll
        for (int rf = 0; rf < 4; ++rf) {
            #pragma unroll
            for (int r = 0; r < 4; ++r) {
                int t = t0 + 64 * w + 16 * rf + 4 * q + r;
                int l = t % LSEQ;
                float4 g0 = *(const float4*)(gates + (size_t)t * NEXP);
                float4 g1 = *(const float4*)(gates + (size_t)t * NEXP + 4);
                const float* bp = bw + (size_t)l * NEXP * DOUT + o;
                float s = 0.0f;
                s += g0.x * (acc[rf][0][r] - bp[0 * DOUT]);
                s += g0.y * (acc[rf][1][r] - bp[1 * DOUT]);
                s += g0.z * (acc[rf][2][r] - bp[2 * DOUT]);
                s += g0.w * (acc[rf][3][r] - bp[3 * DOUT]);
                s += g1.x * (acc[rf][4][r] - bp[4 * DOUT]);
                s += g1.y * (acc[rf][5][r] - bp[5 * DOUT]);
                s += g1.z * (acc[rf][6][r] - bp[6 * DOUT]);
                s += g1.w * (acc[rf][7][r] - bp[7 * DOUT]);
                out[(size_t)t * DOUT + o] = s;
            }
        }
    }
}

// ---------------------------------------------------------------------------
// Fallback fp32 path (verified round 1) — only if ws too small for bf16 bufs.
// ---------------------------------------------------------------------------
__global__ __launch_bounds__(256) void gates_kernel(
    const float* __restrict__ x, const float* __restrict__ wg,
    float* __restrict__ gates)
{
    int t    = blockIdx.x * 4 + (threadIdx.x >> 6);
    int lane = threadIdx.x & 63;
    const float* xr = x + (size_t)t * DIN;
    float acc[NEXP];
    #pragma unroll
    for (int e = 0; e < NEXP; e++) acc[e] = 0.0f;
    for (int i = lane; i < DIN; i += 64) {
        float xv = xr[i];
        const float* wr = wg + (size_t)i * NEXP;
        #pragma unroll
        for (int e = 0; e < NEXP; e++) acc[e] += xv * wr[e];
    }
    #pragma unroll
    for (int e = 0; e < NEXP; e++) {
        #pragma unroll
        for (int m = 32; m > 0; m >>= 1) acc[e] += __shfl_xor(acc[e], m, 64);
    }
    float mx = acc[0];
    #pragma unroll
    for (int e = 1; e < NEXP; e++) mx = fmaxf(mx, acc[e]);
    float ex[NEXP]; float s = 0.0f;
    #pragma unroll
    for (int e = 0; e < NEXP; e++) { ex[e] = __expf(acc[e] - mx); s += ex[e]; }
    float inv = 1.0f / s;
    if (lane == 0) {
        #pragma unroll
        for (int e = 0; e < NEXP; e++) gates[(size_t)t * NEXP + e] = ex[e] * inv;
    }
}

__global__ __launch_bounds__(256) void bw_kernel(
    const float* __restrict__ bias, const float* __restrict__ W,
    float* __restrict__ bw)
{
    int wave = blockIdx.x * 4 + (threadIdx.x >> 6);
    int lane = threadIdx.x & 63;
    int l   = wave / (NEXP * DOUT);
    int rem = wave % (NEXP * DOUT);
    int e   = rem / DOUT;
    int o   = rem % DOUT;
    const float4* br = (const float4*)(bias + ((size_t)e * LSEQ + l) * DIN);
    const float4* wr = (const float4*)(W    + ((size_t)e * DOUT + o) * DIN);
    float acc = 0.0f;
    #pragma unroll
    for (int k = 0; k < 3; ++k) {
        int i4 = lane + 64 * k;
        float4 b = br[i4], w = wr[i4];
        acc += b.x * w.x + b.y * w.y + b.z * w.z + b.w * w.w;
    }
    #pragma unroll
    for (int m = 32; m > 0; m >>= 1) acc += __shfl_xor(acc, m, 64);
    if (lane == 0) bw[((size_t)l * NEXP + e) * DOUT + o] = acc;
}

#define TM  64
#define TO  16
#define KT  32
#define KTP 36

__global__ __launch_bounds__(256) void moe_main_kernel(
    const float* __restrict__ x, const float* __restrict__ W,
    const float* __restrict__ gates, const float* __restrict__ bw,
    float* __restrict__ out)
{
    __shared__ float Xs[TM][KTP];
    __shared__ float Wls[128][KTP];
    const int tid = threadIdx.x;
    const int t0 = blockIdx.x * TM;
    const int o0 = blockIdx.y * TO;
    const int cg = tid & 15;
    const int tg = tid >> 4;
    const int lrow = tid >> 3;
    const int lk4  = (tid & 7) * 4;
    float acc[4][NEXP];
    #pragma unroll
    for (int i = 0; i < 4; i++)
        #pragma unroll
        for (int j = 0; j < NEXP; j++) acc[i][j] = 0.0f;
    for (int k0 = 0; k0 < DIN; k0 += KT) {
        #pragma unroll
        for (int r = 0; r < 2; r++) {
            int row = lrow + 32 * r;
            float4 v = *(const float4*)&x[((size_t)(t0 + row)) * DIN + k0 + lk4];
            *(float4*)&Xs[row][lk4] = v;
        }
        #pragma unroll
        for (int r = 0; r < 4; r++) {
            int nl = lrow + 32 * r;
            int e  = nl >> 4;
            int o  = o0 + (nl & 15);
            float4 v;
            if (o < DOUT)
                v = *(const float4*)&W[((size_t)e * DOUT + o) * DIN + k0 + lk4];
            else
                v = make_float4(0.f, 0.f, 0.f, 0.f);
            *(float4*)&Wls[nl][lk4] = v;
        }
        __syncthreads();
        #pragma unroll
        for (int k4 = 0; k4 < KT; k4 += 4) {
            float4 xa[4], wb4[NEXP];
            #pragma unroll
            for (int i = 0; i < 4; i++)
                xa[i] = *(const float4*)&Xs[tg + 16 * i][k4];
            #pragma unroll
            for (int j = 0; j < NEXP; j++)
                wb4[j] = *(const float4*)&Wls[cg + 16 * j][k4];
            #pragma unroll
            for (int i = 0; i < 4; i++)
                #pragma unroll
                for (int j = 0; j < NEXP; j++) {
                    acc[i][j] += xa[i].x * wb4[j].x;
                    acc[i][j] += xa[i].y * wb4[j].y;
                    acc[i][j] += xa[i].z * wb4[j].z;
                    acc[i][j] += xa[i].w * wb4[j].w;
                }
        }
        __syncthreads();
    }
    const int o = o0 + cg;
    if (o < DOUT) {
        #pragma unroll
        for (int i = 0; i < 4; i++) {
            int t = t0 + tg + 16 * i;
            int l = t % LSEQ;
            float s = 0.0f;
            #pragma unroll
            for (int j = 0; j < NEXP; j++) {
                float g = gates[(size_t)t * NEXP + j];
                s += g * (acc[i][j] - bw[((size_t)l * NEXP + j) * DOUT + o]);
            }
            out[(size_t)t * DOUT + o] = s;
        }
    }
}

// ---------------------------------------------------------------------------
extern "C" void kernel_launch(void* const* d_in, const int* in_sizes, int n_in,
                              void* d_out, int out_size, void* d_ws, size_t ws_size,
                              hipStream_t stream) {
    const float* x     = (const float*)d_in[0];   // [512,50,768]
    const float* wgate = (const float*)d_in[1];   // [768,8]
    const float* ew    = (const float*)d_in[2];   // [8,300,768]
    const float* ebias = (const float*)d_in[3];   // [8,50,768]
    float* out = (float*)d_out;                   // [512,50,300]

    // ws layout: gates | bw | xb (bf16) | wb (bf16)
    const size_t n_gates = (size_t)NTOK * NEXP;           // 204800 f32
    const size_t n_bw    = (size_t)LSEQ * NEXP * DOUT;    // 120000 f32
    const size_t n_x     = (size_t)NTOK * DIN;            // 19,660,800
    const size_t n_w     = (size_t)NEXP * DOUT * DIN;     // 1,843,200

    float* gates = (float*)d_ws;
    float* bw    = gates + n_gates;
    bf16_t* xb   = (bf16_t*)(bw + n_bw);
    bf16_t* wbuf = xb + n_x;

    const size_t need = (n_gates + n_bw) * 4 + (n_x + n_w) * 2;

    if (ws_size >= need) {
        prep_kernel<<<PREP_GATE_BLOCKS + PREP_BW_BLOCKS, 256, 0, stream>>>(
            x, wgate, ebias, ew, (unsigned short*)xb, gates, bw, (unsigned short*)wbuf);
        moe_mfma8_kernel<<<NSLOT8, 512, 0, stream>>>(xb, wbuf, gates, bw, out);
    } else {
        gates_kernel<<<NTOK / 4, 256, 0, stream>>>(x, wgate, gates);
        bw_kernel<<<(LSEQ * NEXP * DOUT) / 4, 256, 0, stream>>>(ebias, ew, bw);
        dim3 grid(NTOK / TM, (DOUT + TO - 1) / TO);      // 400 x 19
        moe_main_kernel<<<grid, 256, 0, stream>>>(x, ew, gates, bw, out);
    }
}

// Round 7
// 277.016 us; speedup vs baseline: 1.0698x; 1.0698x over previous
//
#include <hip/hip_runtime.h>
#include <hip/hip_bf16.h>

// Problem constants (MoEAdaptorLayer_111669150283)
#define BATCH   512
#define LSEQ    50
#define DIN     768
#define DOUT    300
#define NEXP    8
#define NTOK    (BATCH * LSEQ)      // 25600

typedef __bf16 bf16_t;
typedef __attribute__((ext_vector_type(8))) __bf16 bf16x8;
typedef __attribute__((ext_vector_type(4))) float f32x4;

// async global->LDS, 16 B per lane, dst = wave-uniform base + lane*16
#define GLDS16(g, l) __builtin_amdgcn_global_load_lds( \
    (__attribute__((address_space(1))) void*)(g), \
    (__attribute__((address_space(3))) void*)(l), 16, 0, 0)

static __device__ __forceinline__ unsigned short f2bf(float f) {
    unsigned u = __float_as_uint(f);
    u = (u + 0x7fff + ((u >> 16) & 1)) >> 16;   // round-to-nearest-even
    return (unsigned short)u;
}

// ---------------------------------------------------------------------------
// Kernel 1 (merged prep): block-range split. VERBATIM R0 (verified, ~33 us).
//   blocks [0, 6400):    xb = bf16(x), gates = softmax(x @ w_gate)
//   blocks [6400, 7600): bw[l,e,o] = <bias[e,l,:], W[e,o,:]>, wb = bf16(W)
// ---------------------------------------------------------------------------
#define PREP_GATE_BLOCKS (NTOK / 4)              // 6400
#define PREP_BW_BLOCKS   ((2 * NEXP * DOUT) / 4) // 1200

__global__ __launch_bounds__(256) void prep_kernel(
    const float* __restrict__ x, const float* __restrict__ wg,
    const float* __restrict__ bias, const float* __restrict__ W,
    unsigned short* __restrict__ xb, float* __restrict__ gates,
    float* __restrict__ bw, unsigned short* __restrict__ wb)
{
    const int tid  = threadIdx.x;
    const int lane = tid & 63;

    if (blockIdx.x < PREP_GATE_BLOCKS) {
        __shared__ float wgT[NEXP][DIN + 4];   // transposed gate weights
        #pragma unroll
        for (int r = 0; r < 6; ++r) {
            int j = tid + 256 * r;             // float4 index 0..1535
            float4 v = ((const float4*)wg)[j];
            int i  = j >> 1;
            int e0 = (j & 1) * 4;
            wgT[e0 + 0][i] = v.x;
            wgT[e0 + 1][i] = v.y;
            wgT[e0 + 2][i] = v.z;
            wgT[e0 + 3][i] = v.w;
        }
        __syncthreads();

        int t = blockIdx.x * 4 + (tid >> 6);
        const float4* xr = (const float4*)(x + (size_t)t * DIN);
        ushort4* xo = (ushort4*)(xb + (size_t)t * DIN);

        float acc[NEXP];
        #pragma unroll
        for (int e = 0; e < NEXP; e++) acc[e] = 0.0f;

        #pragma unroll
        for (int k = 0; k < 3; ++k) {
            int i4 = lane + 64 * k;
            float4 v = xr[i4];
            ushort4 u;
            u.x = f2bf(v.x); u.y = f2bf(v.y); u.z = f2bf(v.z); u.w = f2bf(v.w);
            xo[i4] = u;
            #pragma unroll
            for (int e = 0; e < NEXP; ++e) {
                float4 wv = *(const float4*)&wgT[e][4 * i4];
                acc[e] += v.x * wv.x + v.y * wv.y + v.z * wv.z + v.w * wv.w;
            }
        }
        #pragma unroll
        for (int e = 0; e < NEXP; e++) {
            #pragma unroll
            for (int m = 32; m > 0; m >>= 1) acc[e] += __shfl_xor(acc[e], m, 64);
        }
        float mx = acc[0];
        #pragma unroll
        for (int e = 1; e < NEXP; e++) mx = fmaxf(mx, acc[e]);
        float ex[NEXP]; float s = 0.0f;
        #pragma unroll
        for (int e = 0; e < NEXP; e++) { ex[e] = __expf(acc[e] - mx); s += ex[e]; }
        float inv = 1.0f / s;
        if (lane == 0) {
            #pragma unroll
            for (int e = 0; e < NEXP; e++) gates[(size_t)t * NEXP + e] = ex[e] * inv;
        }
    } else {
        int wid  = (blockIdx.x - PREP_GATE_BLOCKS) * 4 + (tid >> 6);  // 0..4799
        int half = wid & 1;
        int eo   = wid >> 1;
        int e = eo / DOUT, o = eo % DOUT;

        const float4* wr = (const float4*)(W + ((size_t)e * DOUT + o) * DIN);
        float4 w4[3];
        #pragma unroll
        for (int k = 0; k < 3; ++k) w4[k] = wr[lane + 64 * k];

        if (half == 0) {
            ushort4* wo = (ushort4*)(wb + ((size_t)e * DOUT + o) * DIN);
            #pragma unroll
            for (int k = 0; k < 3; ++k) {
                ushort4 u;
                u.x = f2bf(w4[k].x); u.y = f2bf(w4[k].y);
                u.z = f2bf(w4[k].z); u.w = f2bf(w4[k].w);
                wo[lane + 64 * k] = u;
            }
        }

        int l0 = 25 * half;
        for (int l = l0; l < l0 + 25; ++l) {
            const float4* br = (const float4*)(bias + ((size_t)e * LSEQ + l) * DIN);
            float acc = 0.0f;
            #pragma unroll
            for (int k = 0; k < 3; ++k) {
                float4 b = br[lane + 64 * k];
                acc += b.x * w4[k].x + b.y * w4[k].y + b.z * w4[k].z + b.w * w4[k].w;
            }
            #pragma unroll
            for (int m = 32; m > 0; m >>= 1) acc += __shfl_xor(acc, m, 64);
            if (lane == 0) bw[((size_t)l * NEXP + e) * DOUT + o] = acc;
        }
    }
}

// ---------------------------------------------------------------------------
// Kernel 2 (ROUND 12): A-direct MFMA GEMM. R6's single-block phasing failed
// (1 block/CU -> barrier stalls exposed; reverted). R5 books: DS 2112 +
// MFMA 1552 cyc per CU-iter vs wall 4040 -> DS-heavy, no overlap. KEY FIX:
// the A tile has ZERO cross-wave reuse (each wave owns its 64 rows; intra-
// wave reuse is in registers anyway) -> A's LDS round-trip was pure overhead
// (guide lesson #7). A fragments now load DIRECTLY global->VGPR at byte-
// identical addresses to the old GLDS16 pattern (same HBM/L2 traffic).
// Only B (8 KB, shared by 4 waves) stays in LDS: proven GLDS16 double-buffer.
// DS volume drops 84->40 reads/block-iter + writes 28K->8K -> MFMA-capped.
// Single barrier per iter (canonical T3): reads complete per-wave before its
// MFMA (lgkmcnt(0)); barrier at iter top separates last iter's readers from
// this iter's B-stage overwrite. vmcnt ledger (per wave):
//   top: A_j(4 new)+B_j(2 old) -> vmcnt(4) waits B_j only
//   pre-MFMA: B_{j+1}(2 new)+A_j -> vmcnt(2) waits A_j (aged ~barrier+reads)
//   tail (no B_24): vmcnt(0).
// Geometry: R3-proven 256x128 block, 4 waves of 64x128 (rf4 x cf8), XCD grid,
// epilogue VERBATIM. LDS = 2 x 8 KB only.
// ---------------------------------------------------------------------------
#define GTM 256            // tokens per block
#define GTO 16             // outputs per block (x 8 experts = 128 cols)
#define GKIT (DIN / 32)    // 24 K-tiles
#define NRT  (NTOK / GTM)  // 100 row tiles
#define NOT  19            // o tiles
#define RPG  13            // row-tiles per XCD group (8*13=104 >= 100)
#define NSLOT (8 * RPG * NOT)   // 1976
#define BBUF 8192          // one B buffer (128 rows x 64 B)

__global__ __launch_bounds__(256, 2) void moe_mfma_kernel(
    const bf16_t* __restrict__ xb, const bf16_t* __restrict__ wb,
    const float* __restrict__ gates, const float* __restrict__ bw,
    float* __restrict__ out)
{
    // grid decode: bid = slot*8 + g; slot = r_in*19 + o_t; r_t = g*13 + r_in
    const int bid  = blockIdx.x;
    const int g    = bid & 7;
    const int slot = bid >> 3;
    const int r_in = slot / NOT;
    const int o_t  = slot - NOT * r_in;
    const int r_t  = g * RPG + r_in;
    if (r_t >= NRT) return;            // uniform early-exit (before any barrier)
    const int o0 = o_t * GTO;
    const int t0 = r_t * GTM;

    __shared__ __align__(16) char lds[2 * BBUF];   // 16384 B: B double-buffer

    const int tid  = threadIdx.x;
    const int w    = tid >> 6;
    const int lane = tid & 63;

    // ---- B staging (swizzle scheme verified rounds 2-5) ----
    const int srow4 = lane >> 2;                          // 0..15
    const int c16   = 16 * ((lane & 3) ^ ((lane >> 4) & 3));

    const char* wq[2];
    #pragma unroll
    for (int j = 0; j < 2; ++j) {
        int n = 32 * w + 16 * j + srow4;
        int e = n >> 4;
        int o = o0 + (n & 15); if (o >= DOUT) o = DOUT - 1;  // clamp; guarded at store
        wq[j] = (const char*)wb + (size_t)(e * DOUT + o) * (DIN * 2) + c16;
    }

    // ---- fragment addressing ----
    const int m = lane & 15, q = lane >> 4;
    const int sw = 16 * (q ^ ((m >> 2) & 3));
    int boff[8];
    #pragma unroll
    for (int cf = 0; cf < 8; ++cf) boff[cf] = (16 * cf + m) * 64 + sw;

    // A direct-from-global: lane (m,q) of frag rf reads 16 B at
    // row = t0 + 64w + 16rf + m, byte = row*1536 + k0 + q*16. No swizzle
    // needed (that was an LDS-bank concern). 4 lanes (q=0..3) cover one
    // contiguous 64-B row segment -> same coalescing as the old GLDS16.
    const char* xga[4];
    #pragma unroll
    for (int rf = 0; rf < 4; ++rf)
        xga[rf] = (const char*)xb + (size_t)(t0 + 64 * w + 16 * rf + m) * (DIN * 2) + q * 16;

    f32x4 acc[4][8] = {};

    // ---- prologue: stage B tile 0 into buf0 (2 glds, no wait) ----
    GLDS16(wq[0], lds + 2048 * w);
    GLDS16(wq[1], lds + 2048 * w + 1024);
    #pragma unroll
    for (int j = 0; j < 2; ++j) wq[j] += 64;

    for (int it = 0; it < GKIT; ++it) {
        const int cur = it & 1;

        // [1] A_j: 4 x global_load_dwordx4 -> regs (vmem +4, not waited yet)
        bf16x8 a0 = *(const bf16x8*)(xga[0]);
        bf16x8 a1 = *(const bf16x8*)(xga[1]);
        bf16x8 a2 = *(const bf16x8*)(xga[2]);
        bf16x8 a3 = *(const bf16x8*)(xga[3]);
        #pragma unroll
        for (int rf = 0; rf < 4; ++rf) xga[rf] += 64;

        // [2] wait B_j glds (2, issued last iter; A_j are the 4 newest)
        asm volatile("s_waitcnt vmcnt(4)" ::: "memory");
        // [3] B_j visible block-wide; buf[cur^1] readers (iter it-1) done
        __builtin_amdgcn_s_barrier();
        __builtin_amdgcn_sched_barrier(0);

        // [4] stage B_{j+1} into buf[cur^1] (vmem +2)
        if (it + 1 < GKIT) {
            char* nb = lds + BBUF * (cur ^ 1);
            GLDS16(wq[0], nb + 2048 * w);
            GLDS16(wq[1], nb + 2048 * w + 1024);
            #pragma unroll
            for (int j = 0; j < 2; ++j) wq[j] += 64;
        }

        // [5] B fragment reads from buf[cur]
        const char* cb = lds + BBUF * cur;
        bf16x8 b0 = *(const bf16x8*)(cb + boff[0]);
        bf16x8 b1 = *(const bf16x8*)(cb + boff[1]);
        bf16x8 b2 = *(const bf16x8*)(cb + boff[2]);
        bf16x8 b3 = *(const bf16x8*)(cb + boff[3]);
        bf16x8 b4 = *(const bf16x8*)(cb + boff[4]);
        bf16x8 b5 = *(const bf16x8*)(cb + boff[5]);
        bf16x8 b6 = *(const bf16x8*)(cb + boff[6]);
        bf16x8 b7 = *(const bf16x8*)(cb + boff[7]);

        // [6] A_j done (aged under [2]-[5]) + B reads done; B_{j+1} rides on
        if (it + 1 < GKIT) {
            asm volatile("s_waitcnt vmcnt(2) lgkmcnt(0)" ::: "memory");
        } else {
            asm volatile("s_waitcnt vmcnt(0) lgkmcnt(0)" ::: "memory");
        }
        __builtin_amdgcn_sched_barrier(0);

        // [7] MFMA cluster (32)
        acc[0][0] = __builtin_amdgcn_mfma_f32_16x16x32_bf16(a0, b0, acc[0][0], 0, 0, 0);
        acc[0][1] = __builtin_amdgcn_mfma_f32_16x16x32_bf16(a0, b1, acc[0][1], 0, 0, 0);
        acc[0][2] = __builtin_amdgcn_mfma_f32_16x16x32_bf16(a0, b2, acc[0][2], 0, 0, 0);
        acc[0][3] = __builtin_amdgcn_mfma_f32_16x16x32_bf16(a0, b3, acc[0][3], 0, 0, 0);
        acc[0][4] = __builtin_amdgcn_mfma_f32_16x16x32_bf16(a0, b4, acc[0][4], 0, 0, 0);
        acc[0][5] = __builtin_amdgcn_mfma_f32_16x16x32_bf16(a0, b5, acc[0][5], 0, 0, 0);
        acc[0][6] = __builtin_amdgcn_mfma_f32_16x16x32_bf16(a0, b6, acc[0][6], 0, 0, 0);
        acc[0][7] = __builtin_amdgcn_mfma_f32_16x16x32_bf16(a0, b7, acc[0][7], 0, 0, 0);
        acc[1][0] = __builtin_amdgcn_mfma_f32_16x16x32_bf16(a1, b0, acc[1][0], 0, 0, 0);
        acc[1][1] = __builtin_amdgcn_mfma_f32_16x16x32_bf16(a1, b1, acc[1][1], 0, 0, 0);
        acc[1][2] = __builtin_amdgcn_mfma_f32_16x16x32_bf16(a1, b2, acc[1][2], 0, 0, 0);
        acc[1][3] = __builtin_amdgcn_mfma_f32_16x16x32_bf16(a1, b3, acc[1][3], 0, 0, 0);
        acc[1][4] = __builtin_amdgcn_mfma_f32_16x16x32_bf16(a1, b4, acc[1][4], 0, 0, 0);
        acc[1][5] = __builtin_amdgcn_mfma_f32_16x16x32_bf16(a1, b5, acc[1][5], 0, 0, 0);
        acc[1][6] = __builtin_amdgcn_mfma_f32_16x16x32_bf16(a1, b6, acc[1][6], 0, 0, 0);
        acc[1][7] = __builtin_amdgcn_mfma_f32_16x16x32_bf16(a1, b7, acc[1][7], 0, 0, 0);
        acc[2][0] = __builtin_amdgcn_mfma_f32_16x16x32_bf16(a2, b0, acc[2][0], 0, 0, 0);
        acc[2][1] = __builtin_amdgcn_mfma_f32_16x16x32_bf16(a2, b1, acc[2][1], 0, 0, 0);
        acc[2][2] = __builtin_amdgcn_mfma_f32_16x16x32_bf16(a2, b2, acc[2][2], 0, 0, 0);
        acc[2][3] = __builtin_amdgcn_mfma_f32_16x16x32_bf16(a2, b3, acc[2][3], 0, 0, 0);
        acc[2][4] = __builtin_amdgcn_mfma_f32_16x16x32_bf16(a2, b4, acc[2][4], 0, 0, 0);
        acc[2][5] = __builtin_amdgcn_mfma_f32_16x16x32_bf16(a2, b5, acc[2][5], 0, 0, 0);
        acc[2][6] = __builtin_amdgcn_mfma_f32_16x16x32_bf16(a2, b6, acc[2][6], 0, 0, 0);
        acc[2][7] = __builtin_amdgcn_mfma_f32_16x16x32_bf16(a2, b7, acc[2][7], 0, 0, 0);
        acc[3][0] = __builtin_amdgcn_mfma_f32_16x16x32_bf16(a3, b0, acc[3][0], 0, 0, 0);
        acc[3][1] = __builtin_amdgcn_mfma_f32_16x16x32_bf16(a3, b1, acc[3][1], 0, 0, 0);
        acc[3][2] = __builtin_amdgcn_mfma_f32_16x16x32_bf16(a3, b2, acc[3][2], 0, 0, 0);
        acc[3][3] = __builtin_amdgcn_mfma_f32_16x16x32_bf16(a3, b3, acc[3][3], 0, 0, 0);
        acc[3][4] = __builtin_amdgcn_mfma_f32_16x16x32_bf16(a3, b4, acc[3][4], 0, 0, 0);
        acc[3][5] = __builtin_amdgcn_mfma_f32_16x16x32_bf16(a3, b5, acc[3][5], 0, 0, 0);
        acc[3][6] = __builtin_amdgcn_mfma_f32_16x16x32_bf16(a3, b6, acc[3][6], 0, 0, 0);
        acc[3][7] = __builtin_amdgcn_mfma_f32_16x16x32_bf16(a3, b7, acc[3][7], 0, 0, 0);
    }

    // ---- epilogue: out[t,o] = sum_e g[t,e] * (acc - bw[l,e,o]) (VERBATIM) --
    const int o = o0 + m;
    if (o < DOUT) {
        #pragma unroll
        for (int rf = 0; rf < 4; ++rf) {
            #pragma unroll
            for (int r = 0; r < 4; ++r) {
                int t = t0 + 64 * w + 16 * rf + 4 * q + r;
                int l = t % LSEQ;
                float4 g0 = *(const float4*)(gates + (size_t)t * NEXP);
                float4 g1 = *(const float4*)(gates + (size_t)t * NEXP + 4);
                const float* bp = bw + (size_t)l * NEXP * DOUT + o;
                float s = 0.0f;
                s += g0.x * (acc[rf][0][r] - bp[0 * DOUT]);
                s += g0.y * (acc[rf][1][r] - bp[1 * DOUT]);
                s += g0.z * (acc[rf][2][r] - bp[2 * DOUT]);
                s += g0.w * (acc[rf][3][r] - bp[3 * DOUT]);
                s += g1.x * (acc[rf][4][r] - bp[4 * DOUT]);
                s += g1.y * (acc[rf][5][r] - bp[5 * DOUT]);
                s += g1.z * (acc[rf][6][r] - bp[6 * DOUT]);
                s += g1.w * (acc[rf][7][r] - bp[7 * DOUT]);
                out[(size_t)t * DOUT + o] = s;
            }
        }
    }
}

// ---------------------------------------------------------------------------
// Fallback fp32 path (verified round 1) — only if ws too small for bf16 bufs.
// ---------------------------------------------------------------------------
__global__ __launch_bounds__(256) void gates_kernel(
    const float* __restrict__ x, const float* __restrict__ wg,
    float* __restrict__ gates)
{
    int t    = blockIdx.x * 4 + (threadIdx.x >> 6);
    int lane = threadIdx.x & 63;
    const float* xr = x + (size_t)t * DIN;
    float acc[NEXP];
    #pragma unroll
    for (int e = 0; e < NEXP; e++) acc[e] = 0.0f;
    for (int i = lane; i < DIN; i += 64) {
        float xv = xr[i];
        const float* wr = wg + (size_t)i * NEXP;
        #pragma unroll
        for (int e = 0; e < NEXP; e++) acc[e] += xv * wr[e];
    }
    #pragma unroll
    for (int e = 0; e < NEXP; e++) {
        #pragma unroll
        for (int m = 32; m > 0; m >>= 1) acc[e] += __shfl_xor(acc[e], m, 64);
    }
    float mx = acc[0];
    #pragma unroll
    for (int e = 1; e < NEXP; e++) mx = fmaxf(mx, acc[e]);
    float ex[NEXP]; float s = 0.0f;
    #pragma unroll
    for (int e = 0; e < NEXP; e++) { ex[e] = __expf(acc[e] - mx); s += ex[e]; }
    float inv = 1.0f / s;
    if (lane == 0) {
        #pragma unroll
        for (int e = 0; e < NEXP; e++) gates[(size_t)t * NEXP + e] = ex[e] * inv;
    }
}

__global__ __launch_bounds__(256) void bw_kernel(
    const float* __restrict__ bias, const float* __restrict__ W,
    float* __restrict__ bw)
{
    int wave = blockIdx.x * 4 + (threadIdx.x >> 6);
    int lane = threadIdx.x & 63;
    int l   = wave / (NEXP * DOUT);
    int rem = wave % (NEXP * DOUT);
    int e   = rem / DOUT;
    int o   = rem % DOUT;
    const float4* br = (const float4*)(bias + ((size_t)e * LSEQ + l) * DIN);
    const float4* wr = (const float4*)(W    + ((size_t)e * DOUT + o) * DIN);
    float acc = 0.0f;
    #pragma unroll
    for (int k = 0; k < 3; ++k) {
        int i4 = lane + 64 * k;
        float4 b = br[i4], w = wr[i4];
        acc += b.x * w.x + b.y * w.y + b.z * w.z + b.w * w.w;
    }
    #pragma unroll
    for (int m = 32; m > 0; m >>= 1) acc += __shfl_xor(acc, m, 64);
    if (lane == 0) bw[((size_t)l * NEXP + e) * DOUT + o] = acc;
}

#define TM  64
#define TO  16
#define KT  32
#define KTP 36

__global__ __launch_bounds__(256) void moe_main_kernel(
    const float* __restrict__ x, const float* __restrict__ W,
    const float* __restrict__ gates, const float* __restrict__ bw,
    float* __restrict__ out)
{
    __shared__ float Xs[TM][KTP];
    __shared__ float Wls[128][KTP];
    const int tid = threadIdx.x;
    const int t0 = blockIdx.x * TM;
    const int o0 = blockIdx.y * TO;
    const int cg = tid & 15;
    const int tg = tid >> 4;
    const int lrow = tid >> 3;
    const int lk4  = (tid & 7) * 4;
    float acc[4][NEXP];
    #pragma unroll
    for (int i = 0; i < 4; i++)
        #pragma unroll
        for (int j = 0; j < NEXP; j++) acc[i][j] = 0.0f;
    for (int k0 = 0; k0 < DIN; k0 += KT) {
        #pragma unroll
        for (int r = 0; r < 2; r++) {
            int row = lrow + 32 * r;
            float4 v = *(const float4*)&x[((size_t)(t0 + row)) * DIN + k0 + lk4];
            *(float4*)&Xs[row][lk4] = v;
        }
        #pragma unroll
        for (int r = 0; r < 4; r++) {
            int nl = lrow + 32 * r;
            int e  = nl >> 4;
            int o  = o0 + (nl & 15);
            float4 v;
            if (o < DOUT)
                v = *(const float4*)&W[((size_t)e * DOUT + o) * DIN + k0 + lk4];
            else
                v = make_float4(0.f, 0.f, 0.f, 0.f);
            *(float4*)&Wls[nl][lk4] = v;
        }
        __syncthreads();
        #pragma unroll
        for (int k4 = 0; k4 < KT; k4 += 4) {
            float4 xa[4], wb4[NEXP];
            #pragma unroll
            for (int i = 0; i < 4; i++)
                xa[i] = *(const float4*)&Xs[tg + 16 * i][k4];
            #pragma unroll
            for (int j = 0; j < NEXP; j++)
                wb4[j] = *(const float4*)&Wls[cg + 16 * j][k4];
            #pragma unroll
            for (int i = 0; i < 4; i++)
                #pragma unroll
                for (int j = 0; j < NEXP; j++) {
                    acc[i][j] += xa[i].x * wb4[j].x;
                    acc[i][j] += xa[i].y * wb4[j].y;
                    acc[i][j] += xa[i].z * wb4[j].z;
                    acc[i][j] += xa[i].w * wb4[j].w;
                }
        }
        __syncthreads();
    }
    const int o = o0 + cg;
    if (o < DOUT) {
        #pragma unroll
        for (int i = 0; i < 4; i++) {
            int t = t0 + tg + 16 * i;
            int l = t % LSEQ;
            float s = 0.0f;
            #pragma unroll
            for (int j = 0; j < NEXP; j++) {
                float g = gates[(size_t)t * NEXP + j];
                s += g * (acc[i][j] - bw[((size_t)l * NEXP + j) * DOUT + o]);
            }
            out[(size_t)t * DOUT + o] = s;
        }
    }
}

// ---------------------------------------------------------------------------
extern "C" void kernel_launch(void* const* d_in, const int* in_sizes, int n_in,
                              void* d_out, int out_size, void* d_ws, size_t ws_size,
                              hipStream_t stream) {
    const float* x     = (const float*)d_in[0];   // [512,50,768]
    const float* wgate = (const float*)d_in[1];   // [768,8]
    const float* ew    = (const float*)d_in[2];   // [8,300,768]
    const float* ebias = (const float*)d_in[3];   // [8,50,768]
    float* out = (float*)d_out;                   // [512,50,300]

    // ws layout: gates | bw | xb (bf16) | wb (bf16)
    const size_t n_gates = (size_t)NTOK * NEXP;           // 204800 f32
    const size_t n_bw    = (size_t)LSEQ * NEXP * DOUT;    // 120000 f32
    const size_t n_x     = (size_t)NTOK * DIN;            // 19,660,800
    const size_t n_w     = (size_t)NEXP * DOUT * DIN;     // 1,843,200

    float* gates = (float*)d_ws;
    float* bw    = gates + n_gates;
    bf16_t* xb   = (bf16_t*)(bw + n_bw);
    bf16_t* wbuf = xb + n_x;

    const size_t need = (n_gates + n_bw) * 4 + (n_x + n_w) * 2;

    if (ws_size >= need) {
        prep_kernel<<<PREP_GATE_BLOCKS + PREP_BW_BLOCKS, 256, 0, stream>>>(
            x, wgate, ebias, ew, (unsigned short*)xb, gates, bw, (unsigned short*)wbuf);
        moe_mfma_kernel<<<NSLOT, 256, 0, stream>>>(xb, wbuf, gates, bw, out);
    } else {
        gates_kernel<<<NTOK / 4, 256, 0, stream>>>(x, wgate, gates);
        bw_kernel<<<(LSEQ * NEXP * DOUT) / 4, 256, 0, stream>>>(ebias, ew, bw);
        dim3 grid(NTOK / TM, (DOUT + TO - 1) / TO);      // 400 x 19
        moe_main_kernel<<<grid, 256, 0, stream>>>(x, ew, gates, bw, out);
    }
}